// Round 1
// baseline (400.401 us; speedup 1.0000x reference)
//
#include <hip/hip_runtime.h>
#include <hip/hip_bf16.h>

// Problem: out[b,s,f] = sum_e z[e]*W[f,e] + b[f], where z depends only on the
// gate parameters (not x). So the entire (B,S,E)=(8,8192,1024) output is one
// 1024-float vector y broadcast over 65536 rows. Store-BW bound: 256 MB writes.

#define E 1024

// ---- Kernel 1: per-wire single-qubit state -> <Z> --------------------------
__global__ void zvec_kernel(const float* __restrict__ bs_theta,
                            const float* __restrict__ bs_phi,
                            const float* __restrict__ phases,
                            const float* __restrict__ squeeze_r,
                            const float* __restrict__ displacement_r,
                            float* __restrict__ z) {
    int e = blockIdx.x * blockDim.x + threadIdx.x;
    if (e >= E) return;

    // |0> -> rx(bs_theta) -> ry(bs_phi)   (wire-uniform scalars)
    float h1 = 0.5f * bs_theta[0];
    float c1 = cosf(h1), s1 = sinf(h1);
    float h2 = 0.5f * bs_phi[0];
    float c2 = cosf(h2), s2 = sinf(h2);
    // after rx: a=(c1,0), b=(0,-s1); after ry: a'=c2*a - s2*b, b'=s2*a + c2*b
    float ar = c2 * c1, ai = s2 * s1;
    float br = s2 * c1, bi = -c2 * s1;

    // rz(phases[e]): a *= p, b *= conj(p), p = exp(-i*ph/2)
    float hp = 0.5f * phases[e];
    float pr = cosf(hp), pi = -sinf(hp);
    float nar = ar * pr - ai * pi, nai = ar * pi + ai * pr;
    float nbr = br * pr + bi * pi, nbi = bi * pr - br * pi;
    ar = nar; ai = nai; br = nbr; bi = nbi;

    // ry(squeeze_r[e]): a' = c*a - s*b ; b' = s*a + c*b  (real rotation)
    float hs = 0.5f * squeeze_r[e];
    float cs = cosf(hs), ss = sinf(hs);
    nar = cs * ar - ss * br; nai = cs * ai - ss * bi;
    nbr = ss * ar + cs * br; nbi = ss * ai + cs * bi;
    ar = nar; ai = nai; br = nbr; bi = nbi;

    // rx(displacement_r[e]): a' = c*a - i*s*b ; b' = -i*s*a + c*b
    float hd = 0.5f * displacement_r[e];
    float cd = cosf(hd), sd = sinf(hd);
    nar = cd * ar + sd * bi; nai = cd * ai - sd * br;
    nbr = sd * ai + cd * br; nbi = cd * bi - sd * ar;

    // rz(kerr) preserves |a|,|b| -> skip.  <Z> = |a|^2 - |b|^2
    z[e] = (nar * nar + nai * nai) - (nbr * nbr + nbi * nbi);
}

// ---- Kernel 2: y[f] = b[f] + sum_e W[f,e]*z[e] -----------------------------
__global__ void matvec_kernel(const float* __restrict__ W,
                              const float* __restrict__ z,
                              const float* __restrict__ bias,
                              float* __restrict__ y) {
    int f = blockIdx.x;                       // 1024 blocks
    const float* row = W + (size_t)f * E;
    float p = 0.f;
    for (int e = threadIdx.x; e < E; e += 256) p += row[e] * z[e];
    #pragma unroll
    for (int o = 32; o > 0; o >>= 1) p += __shfl_down(p, o, 64);
    __shared__ float sm[4];
    int lane = threadIdx.x & 63, wv = threadIdx.x >> 6;
    if (lane == 0) sm[wv] = p;
    __syncthreads();
    if (threadIdx.x == 0) y[f] = sm[0] + sm[1] + sm[2] + sm[3] + bias[f];
}

// ---- Kernel 3: broadcast y over 65536 rows (float4 stores) -----------------
__global__ void __launch_bounds__(256)
bcast_kernel(const float* __restrict__ y, float4* __restrict__ out, long n4) {
    __shared__ float4 sy[E / 4];              // 4 KB
    for (int i = threadIdx.x; i < E / 4; i += 256)
        sy[i] = ((const float4*)y)[i];
    __syncthreads();
    long stride = (long)gridDim.x * 256;
    for (long i = (long)blockIdx.x * 256 + threadIdx.x; i < n4; i += stride)
        out[i] = sy[i & (E / 4 - 1)];
}

extern "C" void kernel_launch(void* const* d_in, const int* in_sizes, int n_in,
                              void* d_out, int out_size, void* d_ws, size_t ws_size,
                              hipStream_t stream) {
    const float* bs_theta       = (const float*)d_in[1];
    const float* bs_phi         = (const float*)d_in[2];
    const float* phases         = (const float*)d_in[3];
    const float* squeeze_r      = (const float*)d_in[4];
    const float* displacement_r = (const float*)d_in[5];
    const float* W_combine      = (const float*)d_in[7];
    const float* b_combine      = (const float*)d_in[8];

    float* z = (float*)d_ws;          // E floats
    float* y = z + E;                 // E floats

    zvec_kernel<<<1, E, 0, stream>>>(bs_theta, bs_phi, phases, squeeze_r,
                                     displacement_r, z);
    matvec_kernel<<<E, 256, 0, stream>>>(W_combine, z, b_combine, y);

    long n4 = (long)out_size / 4;     // 64M floats -> 16M float4
    int grid = 16384;                 // 4M threads, 4 float4 stores each
    bcast_kernel<<<grid, 256, 0, stream>>>(y, (float4*)d_out, n4);
}

// Round 2
// 399.643 us; speedup vs baseline: 1.0019x; 1.0019x over previous
//
#include <hip/hip_runtime.h>
#include <hip/hip_bf16.h>

// out[b,s,f] = sum_e z[e]*W[f,e] + b[f]; z depends only on gate params, so the
// whole (8,8192,1024) output is one 1024-float vector y broadcast over 65536
// rows. Floor: 256 MB of stores ~= 41 us at 6.4 TB/s fill rate.
//
// Structure: 2 kernels.
//  A) y_kernel: 1024 blocks; each block recomputes the z vector (cheap trig)
//     into LDS, then dots one W row against it. One launch instead of two.
//  B) bcast_kernel: register-resident row broadcast, pure store stream.

#define E 1024

// ---- Kernel A: y[f] = b[f] + sum_e W[f,e]*z[e], z recomputed per block -----
__global__ void __launch_bounds__(256)
y_kernel(const float* __restrict__ bs_theta,
         const float* __restrict__ bs_phi,
         const float* __restrict__ phases,
         const float* __restrict__ squeeze_r,
         const float* __restrict__ displacement_r,
         const float* __restrict__ W,
         const float* __restrict__ bias,
         float* __restrict__ y) {
    __shared__ float zs[E];

    // wire-uniform prefix: |0> -> rx(bs_theta) -> ry(bs_phi)
    float h1 = 0.5f * bs_theta[0];
    float c1 = cosf(h1), s1 = sinf(h1);
    float h2 = 0.5f * bs_phi[0];
    float c2 = cosf(h2), s2 = sinf(h2);
    float ar0 = c2 * c1, ai0 = s2 * s1;
    float br0 = s2 * c1, bi0 = -c2 * s1;

    #pragma unroll
    for (int k = 0; k < E / 256; ++k) {
        int e = threadIdx.x + k * 256;
        float ar = ar0, ai = ai0, br = br0, bi = bi0;

        // rz(phases[e])
        float hp = 0.5f * phases[e];
        float pr = cosf(hp), pi = -sinf(hp);
        float nar = ar * pr - ai * pi, nai = ar * pi + ai * pr;
        float nbr = br * pr + bi * pi, nbi = bi * pr - br * pi;
        ar = nar; ai = nai; br = nbr; bi = nbi;

        // ry(squeeze_r[e])
        float hs = 0.5f * squeeze_r[e];
        float cs = cosf(hs), ss = sinf(hs);
        nar = cs * ar - ss * br; nai = cs * ai - ss * bi;
        nbr = ss * ar + cs * br; nbi = ss * ai + cs * bi;
        ar = nar; ai = nai; br = nbr; bi = nbi;

        // rx(displacement_r[e])
        float hd = 0.5f * displacement_r[e];
        float cd = cosf(hd), sd = sinf(hd);
        nar = cd * ar + sd * bi; nai = cd * ai - sd * br;
        nbr = sd * ai + cd * br; nbi = cd * bi - sd * ar;

        // rz(kerr) preserves magnitudes -> skip. <Z> = |a|^2 - |b|^2
        zs[e] = (nar * nar + nai * nai) - (nbr * nbr + nbi * nbi);
    }
    __syncthreads();

    int f = blockIdx.x;
    const float4* row4 = (const float4*)(W + (size_t)f * E);
    float4 w = row4[threadIdx.x];
    float4 zv = ((const float4*)zs)[threadIdx.x];
    float p = w.x * zv.x + w.y * zv.y + w.z * zv.z + w.w * zv.w;

    #pragma unroll
    for (int o = 32; o > 0; o >>= 1) p += __shfl_down(p, o, 64);
    __shared__ float sm[4];
    int lane = threadIdx.x & 63, wv = threadIdx.x >> 6;
    if (lane == 0) sm[wv] = p;
    __syncthreads();
    if (threadIdx.x == 0) y[f] = sm[0] + sm[1] + sm[2] + sm[3] + bias[f];
}

// ---- Kernel B: broadcast y over rows; value lives in a register ------------
__global__ void __launch_bounds__(256)
bcast_kernel(const float4* __restrict__ y4, float4* __restrict__ out,
             int rows_per_block) {
    float4 v = y4[threadIdx.x];                 // 256 thr x float4 = one row
    long base = (long)blockIdx.x * rows_per_block * (E / 4) + threadIdx.x;
    #pragma unroll 4
    for (int r = 0; r < rows_per_block; ++r)
        out[base + (long)r * (E / 4)] = v;
}

extern "C" void kernel_launch(void* const* d_in, const int* in_sizes, int n_in,
                              void* d_out, int out_size, void* d_ws, size_t ws_size,
                              hipStream_t stream) {
    const float* bs_theta       = (const float*)d_in[1];
    const float* bs_phi         = (const float*)d_in[2];
    const float* phases         = (const float*)d_in[3];
    const float* squeeze_r      = (const float*)d_in[4];
    const float* displacement_r = (const float*)d_in[5];
    const float* W_combine      = (const float*)d_in[7];
    const float* b_combine      = (const float*)d_in[8];

    float* y = (float*)d_ws;          // E floats

    y_kernel<<<E, 256, 0, stream>>>(bs_theta, bs_phi, phases, squeeze_r,
                                    displacement_r, W_combine, b_combine, y);

    int rows = out_size / E;          // 65536
    int rows_per_block = 8;
    int grid = rows / rows_per_block; // 8192 blocks
    bcast_kernel<<<grid, 256, 0, stream>>>((const float4*)y, (float4*)d_out,
                                           rows_per_block);
}